// Round 3
// baseline (802.462 us; speedup 1.0000x reference)
//
#include <hip/hip_runtime.h>
#include <hip/hip_cooperative_groups.h>

// LinkPrediction: per-edge 2-layer MLP routed by edge type (MoE-style).
// outputs: [0..N_EDGES) = scores, [N_EDGES..) = copy of rgcn_emb.
//
// R6 theory: score=86us but total=287us in BOTH R0/R2 structures; prep work
// sums to ~60us -> ~130-140us scales with the NUMBER of serialized
// dispatches, not their work. Also f16 convert is negative-ROI (256MB pass
// to save ~30us in a latency-bound kernel).
//  => ONE cooperative mega-kernel, grid.sync between phases, fp32 score:
//   A: per-chunk type counts (128 blk, no atomics->no memset)
//      || copy emb->out (normal loads warm LLC for the gathers; NT stores)
//   B: 1-block prefix scan (counts, poff, per-chunk bases)
//   C: scatter into reserved slots (LDS-local atomics only)
//   D: fp32 score on type-sorted edges (wave-uniform type -> scalar W loads)
//  __launch_bounds__(256,7) caps VGPR<=72 -> 7 blk/CU -> 1792 co-resident
//  blocks >= 1571 score work-blocks (single round). Fallback: same phases as
//  4 plain launches if cooperative launch is unavailable.

namespace cg = cooperative_groups;

typedef float f4 __attribute__((ext_vector_type(4)));

constexpr int N_NODES = 200000;
constexpr int N_EDGES = 400000;
constexpr int EMB_DIM = 128;
constexpr int HID     = 24;
constexpr int N_TYPES = 8;
constexpr int BLK     = 256;

constexpr int CHUNKS  = 128;
constexpr int CH_SZ   = N_EDGES / CHUNKS;                  // 3125 exact
constexpr int MAX_PAD = N_EDGES + N_TYPES * (BLK - 1);     // 402040
constexpr int SCORE_BLOCKS = (MAX_PAD + BLK - 1) / BLK;    // 1571

// ws int offsets
constexpr int OFF_COUNTS = 0;                              // [8]
constexpr int OFF_POFF   = 8;                              // [8]
constexpr int OFF_CC     = 16;                             // [CHUNKS*8]
constexpr int OFF_BASE   = OFF_CC + CHUNKS * N_TYPES;      // [CHUNKS*8]
constexpr int OFF_SORTED = OFF_BASE + CHUNKS * N_TYPES;    // [MAX_PAD]
constexpr size_t WS_INTS = (size_t)OFF_SORTED + MAX_PAD;

// ---------------- phase bodies ----------------

__device__ __forceinline__ void phaseA(int b, int G,
        const int* __restrict__ etype, const float* __restrict__ emb,
        float* __restrict__ out, int* __restrict__ ws) {
    if (b < CHUNKS) {
        __shared__ int lc[N_TYPES];
        if (threadIdx.x < N_TYPES) lc[threadIdx.x] = 0;
        __syncthreads();
        int e0 = b * CH_SZ;
        for (int e = e0 + (int)threadIdx.x; e < e0 + CH_SZ; e += BLK)
            atomicAdd(&lc[etype[e]], 1);
        __syncthreads();
        if (threadIdx.x < N_TYPES)
            ws[OFF_CC + b * N_TYPES + threadIdx.x] = lc[threadIdx.x];
    } else {
        const f4* in4 = (const f4*)emb;
        f4* o4 = (f4*)(out + N_EDGES);
        const int n4 = N_NODES * EMB_DIM / 4;              // 6.4M
        int nb = G - CHUNKS;
        for (int i = (b - CHUNKS) * BLK + (int)threadIdx.x; i < n4; i += nb * BLK) {
            f4 a = in4[i];                                 // normal load: warm LLC
            __builtin_nontemporal_store(a, &o4[i]);        // copy never re-read
        }
    }
}

__device__ __forceinline__ void phaseB(int b, int* __restrict__ ws) {
    if (b == 0) {
        if (threadIdx.x < N_TYPES) {
            int t = threadIdx.x;
            int s = 0;
            for (int c = 0; c < CHUNKS; ++c) {
                ws[OFF_BASE + c * N_TYPES + t] = s;        // exclusive prefix
                s += ws[OFF_CC + c * N_TYPES + t];
            }
            ws[OFF_COUNTS + t] = s;
        }
        __syncthreads();
        if (threadIdx.x == 0) {
            int off = 0;
            for (int t = 0; t < N_TYPES; ++t) {
                ws[OFF_POFF + t] = off;
                off += ((ws[OFF_COUNTS + t] + BLK - 1) / BLK) * BLK;
            }
        }
    }
}

__device__ __forceinline__ void phaseC(int b, const int* __restrict__ etype,
                                       int* __restrict__ ws) {
    if (b < CHUNKS) {
        __shared__ int lc[N_TYPES];
        __shared__ int pbase[N_TYPES];
        if (threadIdx.x < N_TYPES) {
            lc[threadIdx.x] = 0;
            pbase[threadIdx.x] = ws[OFF_POFF + threadIdx.x]
                               + ws[OFF_BASE + b * N_TYPES + threadIdx.x];
        }
        __syncthreads();
        int e0 = b * CH_SZ;
        int* sorted = ws + OFF_SORTED;
        for (int e = e0 + (int)threadIdx.x; e < e0 + CH_SZ; e += BLK) {
            int t = etype[e];
            int r = atomicAdd(&lc[t], 1);
            sorted[pbase[t] + r] = e;
        }
    }
}

__device__ __forceinline__ void half_mm(const f4* __restrict__ x4,
                                        const float* __restrict__ w,
                                        float acc[HID]) {
#pragma unroll 1
    for (int c = 0; c < 4; ++c) {                          // 128B per chunk
        f4 r[8];
#pragma unroll
        for (int k = 0; k < 8; ++k) r[k] = x4[c * 8 + k];
#pragma unroll
        for (int k = 0; k < 8; ++k) {
            const float* wp = w + (c * 32 + k * 4) * HID;
#pragma unroll
            for (int j = 0; j < HID; ++j) acc[j] = fmaf(r[k][0], wp[0 * HID + j], acc[j]);
#pragma unroll
            for (int j = 0; j < HID; ++j) acc[j] = fmaf(r[k][1], wp[1 * HID + j], acc[j]);
#pragma unroll
            for (int j = 0; j < HID; ++j) acc[j] = fmaf(r[k][2], wp[2 * HID + j], acc[j]);
#pragma unroll
            for (int j = 0; j < HID; ++j) acc[j] = fmaf(r[k][3], wp[3 * HID + j], acc[j]);
        }
    }
}

__device__ __forceinline__ void phaseD(const float* __restrict__ emb,
        const int* __restrict__ srci, const int* __restrict__ dsti,
        const float* __restrict__ W1, const float* __restrict__ b1,
        const float* __restrict__ W2, const float* __restrict__ b2,
        const int* __restrict__ ws, float* __restrict__ out, int G) {
    int poff[N_TYPES];
    int off = 0;
#pragma unroll
    for (int t = 0; t < N_TYPES; ++t) {
        poff[t] = off;
        off += ((ws[OFF_COUNTS + t] + BLK - 1) / BLK) * BLK;
    }
    const int* sorted = ws + OFF_SORTED;
    for (int wb = (int)blockIdx.x; wb * BLK < off; wb += G) {
        int slot0 = wb * BLK;
        int t = 0;
#pragma unroll
        for (int i = 1; i < N_TYPES; ++i)
            if (slot0 >= poff[i]) t = i;
        t = __builtin_amdgcn_readfirstlane(t);             // wave-uniform type
        int cnt = ws[OFF_COUNTS + t];
        int local = slot0 - poff[t] + (int)threadIdx.x;
        if (local < cnt) {
            int e = sorted[slot0 + threadIdx.x];
            int s = srci[e], d = dsti[e];
            float acc[HID];
#pragma unroll
            for (int j = 0; j < HID; ++j) acc[j] = b1[t * HID + j];
            const float* W1t = W1 + (size_t)t * (2 * EMB_DIM * HID);
            half_mm((const f4*)(emb + (size_t)s * EMB_DIM), W1t, acc);
            half_mm((const f4*)(emb + (size_t)d * EMB_DIM), W1t + EMB_DIM * HID, acc);
            float sc = b2[t];
#pragma unroll
            for (int j = 0; j < HID; ++j) {
                float h = acc[j];
                h = (h > 0.f) ? h : 0.01f * h;             // LeakyReLU(0.01)
                sc = fmaf(h, W2[t * HID + j], sc);
            }
            out[e] = sc;
        }
    }
}

// ---------------- cooperative mega-kernel ----------------

__global__ __launch_bounds__(BLK, 7) void mega_k(
        const float* __restrict__ emb, const int* __restrict__ srci,
        const int* __restrict__ dsti, const int* __restrict__ etype,
        const float* __restrict__ W1, const float* __restrict__ b1,
        const float* __restrict__ W2, const float* __restrict__ b2,
        float* __restrict__ out, int* __restrict__ ws) {
    cg::grid_group grid = cg::this_grid();
    int G = (int)gridDim.x;
    phaseA((int)blockIdx.x, G, etype, emb, out, ws);
    __threadfence();
    grid.sync();
    phaseB((int)blockIdx.x, ws);
    __threadfence();
    grid.sync();
    phaseC((int)blockIdx.x, etype, ws);
    __threadfence();
    grid.sync();
    phaseD(emb, srci, dsti, W1, b1, W2, b2, ws, out, G);
}

// ---------------- non-cooperative fallback (same phases, 4 launches) ----------------

__global__ __launch_bounds__(BLK) void fa_k(const int* __restrict__ etype,
        const float* __restrict__ emb, float* __restrict__ out, int* __restrict__ ws) {
    phaseA((int)blockIdx.x, (int)gridDim.x, etype, emb, out, ws);
}
__global__ __launch_bounds__(BLK) void fb_k(int* __restrict__ ws) {
    phaseB((int)blockIdx.x, ws);
}
__global__ __launch_bounds__(BLK) void fc_k(const int* __restrict__ etype,
                                            int* __restrict__ ws) {
    phaseC((int)blockIdx.x, etype, ws);
}
__global__ __launch_bounds__(BLK) void fd_k(const float* __restrict__ emb,
        const int* __restrict__ srci, const int* __restrict__ dsti,
        const float* __restrict__ W1, const float* __restrict__ b1,
        const float* __restrict__ W2, const float* __restrict__ b2,
        const int* __restrict__ ws, float* __restrict__ out) {
    phaseD(emb, srci, dsti, W1, b1, W2, b2, ws, out, (int)gridDim.x);
}

// ---------------- ws-too-small ultra fallback: correctness only ----------------

__global__ __launch_bounds__(BLK) void fallback_k(
        const float* __restrict__ emb,
        const int* __restrict__ srci, const int* __restrict__ dsti,
        const int* __restrict__ etype,
        const float* __restrict__ W1, const float* __restrict__ b1,
        const float* __restrict__ W2, const float* __restrict__ b2,
        float* __restrict__ out) {
    long long i0 = (long long)blockIdx.x * BLK + threadIdx.x;
    const f4* s4 = (const f4*)emb;
    f4* o4 = (f4*)(out + N_EDGES);
    const long long n4 = (long long)N_NODES * EMB_DIM / 4;
    for (long long i = i0; i < n4; i += (long long)gridDim.x * BLK)
        o4[i] = s4[i];
    for (int e = (int)i0; e < N_EDGES; e += gridDim.x * BLK) {
        int t = etype[e];
        int s = srci[e], d = dsti[e];
        float acc[HID];
#pragma unroll
        for (int j = 0; j < HID; ++j) acc[j] = b1[t * HID + j];
        const float* w = W1 + (size_t)t * 2 * EMB_DIM * HID;
        half_mm((const f4*)(emb + (size_t)s * EMB_DIM), w, acc);
        half_mm((const f4*)(emb + (size_t)d * EMB_DIM), w + EMB_DIM * HID, acc);
        float sc = b2[t];
#pragma unroll
        for (int j = 0; j < HID; ++j) {
            float h = acc[j];
            h = (h > 0.f) ? h : 0.01f * h;
            sc = fmaf(h, W2[t * HID + j], sc);
        }
        out[e] = sc;
    }
}

extern "C" void kernel_launch(void* const* d_in, const int* in_sizes, int n_in,
                              void* d_out, int out_size, void* d_ws, size_t ws_size,
                              hipStream_t stream) {
    const float* emb   = (const float*)d_in[0];
    const int*   eidx  = (const int*)d_in[1];
    const int*   etype = (const int*)d_in[2];
    const float* W1    = (const float*)d_in[3];
    const float* b1    = (const float*)d_in[4];
    const float* W2    = (const float*)d_in[5];
    const float* b2    = (const float*)d_in[6];
    float* out = (float*)d_out;
    const int* srci = eidx;
    const int* dsti = eidx + N_EDGES;

    if (ws_size >= WS_INTS * sizeof(int)) {
        int* ws = (int*)d_ws;
        int nb = 0;
        hipError_t oe = hipOccupancyMaxActiveBlocksPerMultiprocessor(
            &nb, (const void*)mega_k, BLK, 0);
        int G = 0;
        if (oe == hipSuccess && nb > 0) {
            G = nb * 256;                    // nb blocks/CU x 256 CUs
            if (G > 2048) G = 2048;
        }
        bool launched = false;
        if (G >= CHUNKS + 8) {
            void* args[] = {(void*)&emb, (void*)&srci, (void*)&dsti, (void*)&etype,
                            (void*)&W1, (void*)&b1, (void*)&W2, (void*)&b2,
                            (void*)&out, (void*)&ws};
            hipError_t le = hipLaunchCooperativeKernel(
                (const void*)mega_k, dim3(G), dim3(BLK), args, 0, stream);
            launched = (le == hipSuccess);
        }
        if (!launched) {
            fa_k<<<1792, BLK, 0, stream>>>(etype, emb, out, ws);
            fb_k<<<1, BLK, 0, stream>>>(ws);
            fc_k<<<CHUNKS, BLK, 0, stream>>>(etype, ws);
            fd_k<<<SCORE_BLOCKS, BLK, 0, stream>>>(emb, srci, dsti, W1, b1, W2, b2, ws, out);
        }
    } else {
        fallback_k<<<2048, BLK, 0, stream>>>(emb, srci, dsti, etype, W1, b1, W2, b2, out);
    }
}

// Round 4
// 283.401 us; speedup vs baseline: 2.8315x; 2.8315x over previous
//
#include <hip/hip_runtime.h>

// LinkPrediction: per-edge 2-layer MLP routed by edge type (MoE-style).
// outputs: [0..N_EDGES) = scores, [N_EDGES..) = copy of rgcn_emb.
//
// R7 (post coop-launch disaster: grid.sync = ~300us each, VALUBusy 3.4%):
// Facts: score ~86us WITH or WITHOUT fused 204MB copy (R0 vs R2) -> score is
// gather-latency-bound, streaming rides free. So:
//  K1 prep_k:    chunk-hist (no atomics/memset) | W1->f16 | emb->f16.
//                Normal loads/stores: emb+emb16 stay LLC-resident for K3.
//  K2 scatter_k: deterministic scan of chunk-count table per block (no global
//                atomics, no memset); block 0 publishes counts+poff.
//  K3 score16_k: R0-proven f16 gather MLP + fused emb->out copy (free).
// 3 dispatches total, minimal prep traffic (153MB vs R2's 256MB).

typedef _Float16 h2 __attribute__((ext_vector_type(2)));
typedef float    f4 __attribute__((ext_vector_type(4)));

constexpr int N_NODES = 200000;
constexpr int N_EDGES = 400000;
constexpr int EMB_DIM = 128;
constexpr int HID     = 24;
constexpr int N_TYPES = 8;
constexpr int BLK     = 256;

constexpr int CHUNKS  = 128;
constexpr int CH_SZ   = N_EDGES / CHUNKS;                  // 3125 exact
constexpr int MAX_PAD = N_EDGES + N_TYPES * (BLK - 1);     // 402040
constexpr int SCORE_BLOCKS = (MAX_PAD + BLK - 1) / BLK;    // 1571
constexpr int COPY_BLOCKS  = 1024;

constexpr int PREP_HIST = CHUNKS;  // 128 chunk-hist blocks
constexpr int PREP_W1   = 16;
constexpr int PREP_CONV = 1024;
constexpr int PREP_BLOCKS = PREP_HIST + PREP_W1 + PREP_CONV;

// ws int offsets
constexpr int OFF_CC     = 0;                               // [CHUNKS*8]
constexpr int OFF_COUNTS = OFF_CC + CHUNKS * N_TYPES;       // [8]
constexpr int OFF_POFF   = OFF_COUNTS + N_TYPES;            // [8]
constexpr int OFF_SORTED = OFF_POFF + N_TYPES;              // [MAX_PAD]
constexpr size_t SORT_BYTES  = (size_t)(OFF_SORTED + MAX_PAD) * sizeof(int);
constexpr size_t EMB16_OFF   = (SORT_BYTES + 255) & ~(size_t)255;
constexpr size_t EMB16_BYTES = (size_t)N_NODES * EMB_DIM * 2;
constexpr size_t W16_OFF     = EMB16_OFF + EMB16_BYTES;
constexpr size_t W16_BYTES   = (size_t)N_TYPES * 128 * HID * sizeof(int);
constexpr size_t NEED16      = W16_OFF + W16_BYTES;

__device__ __forceinline__ float fdot2f(h2 a, h2 b, float c) {
#if __has_builtin(__builtin_amdgcn_fdot2)
    return __builtin_amdgcn_fdot2(a, b, c, false);
#else
    return c + (float)a[0] * (float)b[0] + (float)a[1] * (float)b[1];
#endif
}

// ---------- K1: chunk-hist | W1 f16 | emb f16 (no copy, no atomics->no memset) ----------
__global__ __launch_bounds__(BLK) void prep_k(
        const int* __restrict__ etype, int* __restrict__ ws,
        const float* __restrict__ emb, int2* __restrict__ emb16,
        const float* __restrict__ W1, h2* __restrict__ w16) {
    int b = blockIdx.x;
    if (b < PREP_HIST) {
        __shared__ int lc[N_TYPES];
        if (threadIdx.x < N_TYPES) lc[threadIdx.x] = 0;
        __syncthreads();
        int e0 = b * CH_SZ;
        for (int e = e0 + (int)threadIdx.x; e < e0 + CH_SZ; e += BLK)
            atomicAdd(&lc[etype[e]], 1);
        __syncthreads();
        if (threadIdx.x < N_TYPES)
            ws[OFF_CC + b * N_TYPES + threadIdx.x] = lc[threadIdx.x];
    } else if (b < PREP_HIST + PREP_W1) {
        int cb = b - PREP_HIST;
        for (int p = cb * BLK + threadIdx.x; p < N_TYPES * 128 * HID; p += PREP_W1 * BLK) {
            int t   = p / (128 * HID);
            int rem = p - t * 128 * HID;
            int kp  = rem / HID, j = rem - kp * HID;
            h2 v;
            v[0] = (_Float16)W1[(t * 256 + 2 * kp)     * HID + j];
            v[1] = (_Float16)W1[(t * 256 + 2 * kp + 1) * HID + j];
            w16[p] = v;
        }
    } else {
        int cb = b - PREP_HIST - PREP_W1;
        const f4* in4 = (const f4*)emb;
        const int n4 = N_NODES * EMB_DIM / 4;               // 6.4M
        for (int i = cb * BLK + threadIdx.x; i < n4; i += PREP_CONV * BLK) {
            f4 a = in4[i];                                  // normal: warm LLC
            union { int2 v; h2 h[2]; } u;
            u.h[0] = h2{(_Float16)a.x, (_Float16)a.y};
            u.h[1] = h2{(_Float16)a.z, (_Float16)a.w};
            emb16[i] = u.v;                                 // normal: keep in LLC
        }
    }
}

// ---------- K2: deterministic scan + scatter (no global atomics) ----------
__global__ __launch_bounds__(BLK) void scatter_k(
        const int* __restrict__ etype, int* __restrict__ ws) {
    __shared__ int sbase[N_TYPES];  // poff[t] + prefix of this chunk
    __shared__ int tot[N_TYPES];
    __shared__ int mybase[N_TYPES];
    __shared__ int spoff[N_TYPES];
    __shared__ int lc[N_TYPES];
    int b = blockIdx.x;
    if (threadIdx.x < N_TYPES) {
        int t = threadIdx.x, s = 0, mb = 0;
        for (int c = 0; c < CHUNKS; ++c) {
            if (c == b) mb = s;
            s += ws[OFF_CC + c * N_TYPES + t];
        }
        tot[t] = s;
        mybase[t] = mb;
        lc[t] = 0;
    }
    __syncthreads();
    if (threadIdx.x == 0) {
        int off = 0;
        for (int t = 0; t < N_TYPES; ++t) {
            spoff[t] = off;
            off += ((tot[t] + BLK - 1) / BLK) * BLK;
        }
    }
    __syncthreads();
    if (threadIdx.x < N_TYPES) {
        sbase[threadIdx.x] = spoff[threadIdx.x] + mybase[threadIdx.x];
        if (b == 0) {                                       // publish for K3
            ws[OFF_COUNTS + threadIdx.x] = tot[threadIdx.x];
            ws[OFF_POFF + threadIdx.x]   = spoff[threadIdx.x];
        }
    }
    __syncthreads();
    int e0 = b * CH_SZ;
    int* sorted = ws + OFF_SORTED;
    for (int e = e0 + (int)threadIdx.x; e < e0 + CH_SZ; e += BLK) {
        int t = etype[e];
        int r = atomicAdd(&lc[t], 1);                       // LDS-local only
        sorted[sbase[t] + r] = e;
    }
}

// ---------- K3: f16 score + fused copy (copy rides free: latency-bound) ----------
__device__ __forceinline__ void do_copy(const float* __restrict__ emb,
                                        float* __restrict__ out, int cb, int nb) {
    const f4* s4 = (const f4*)emb;
    f4* o4 = (f4*)(out + N_EDGES);
    const int n4 = N_NODES * EMB_DIM / 4;
    for (int i = cb * BLK + (int)threadIdx.x; i < n4; i += nb * BLK) {
        f4 a = s4[i];                                       // LLC-hit (K1 warmed)
        __builtin_nontemporal_store(a, &o4[i]);             // never re-read
    }
}

__device__ __forceinline__ void compute_chunk(const int4* __restrict__ r,
                                              const h2* __restrict__ wrow,
                                              float acc[HID]) {
    const h2* hp = (const h2*)r;   // 32 h2 pairs in regs
#pragma unroll
    for (int kp = 0; kp < 32; ++kp) {
#pragma unroll
        for (int j = 0; j < HID; ++j)
            acc[j] = fdot2f(hp[kp], wrow[kp * HID + j], acc[j]);
    }
}

__global__ __launch_bounds__(BLK) void score16_k(
        const unsigned short* __restrict__ emb16u, const float* __restrict__ emb,
        const int* __restrict__ srci, const int* __restrict__ dsti,
        const int* __restrict__ ws,
        const h2* __restrict__ w16, const float* __restrict__ b1,
        const float* __restrict__ W2, const float* __restrict__ b2,
        float* __restrict__ out) {
    int b = blockIdx.x;
    if (b >= SCORE_BLOCKS) {
        do_copy(emb, out, b - SCORE_BLOCKS, (int)gridDim.x - SCORE_BLOCKS);
        return;
    }
    int poff[N_TYPES], counts[N_TYPES];
#pragma unroll
    for (int t = 0; t < N_TYPES; ++t) {
        counts[t] = ws[OFF_COUNTS + t];
        poff[t]   = ws[OFF_POFF + t];
    }
    int off = poff[N_TYPES - 1] + ((counts[N_TYPES - 1] + BLK - 1) / BLK) * BLK;
    int slot0 = b * BLK;
    if (slot0 >= off) return;
    int t = 0;
#pragma unroll
    for (int i = 1; i < N_TYPES; ++i)
        if (slot0 >= poff[i]) t = i;
    t = __builtin_amdgcn_readfirstlane(t);   // wave-uniform type -> scalar W loads
    int cnt = counts[t];
    int local = slot0 - poff[t] + (int)threadIdx.x;
    if (local >= cnt) return;
    const int* sorted = ws + OFF_SORTED;
    int e = sorted[slot0 + threadIdx.x];
    int s = srci[e], d = dsti[e];

    float acc[HID];
#pragma unroll
    for (int j = 0; j < HID; ++j) acc[j] = b1[t * HID + j];
    const h2* wt = w16 + (size_t)t * 128 * HID;
    const int4* x0 = (const int4*)(emb16u + (size_t)s * EMB_DIM);
    const int4* x1 = (const int4*)(emb16u + (size_t)d * EMB_DIM);

    // A/B double buffer: next 128B chunk in flight while current computes.
    int4 A[8], B[8];
#pragma unroll
    for (int k = 0; k < 8; ++k) A[k] = x0[k];
#pragma unroll
    for (int k = 0; k < 8; ++k) B[k] = x0[8 + k];
    compute_chunk(A, wt + 0 * 32 * HID, acc);
#pragma unroll
    for (int k = 0; k < 8; ++k) A[k] = x1[k];
    compute_chunk(B, wt + 1 * 32 * HID, acc);
#pragma unroll
    for (int k = 0; k < 8; ++k) B[k] = x1[8 + k];
    compute_chunk(A, wt + 2 * 32 * HID, acc);
    compute_chunk(B, wt + 3 * 32 * HID, acc);

    float sc = b2[t];
#pragma unroll
    for (int j = 0; j < HID; ++j) {
        float h = acc[j];
        h = (h > 0.f) ? h : 0.01f * h;       // LeakyReLU(0.01)
        sc = fmaf(h, W2[t * HID + j], sc);
    }
    out[e] = sc;
}

// ---------- ws-too-small fallback: correctness only ----------
__global__ __launch_bounds__(BLK) void fallback_k(
        const float* __restrict__ emb,
        const int* __restrict__ srci, const int* __restrict__ dsti,
        const int* __restrict__ etype,
        const float* __restrict__ W1, const float* __restrict__ b1,
        const float* __restrict__ W2, const float* __restrict__ b2,
        float* __restrict__ out) {
    long long i0 = (long long)blockIdx.x * BLK + threadIdx.x;
    const f4* s4 = (const f4*)emb;
    f4* o4 = (f4*)(out + N_EDGES);
    const long long n4 = (long long)N_NODES * EMB_DIM / 4;
    for (long long i = i0; i < n4; i += (long long)gridDim.x * BLK)
        o4[i] = s4[i];
    for (int e = (int)i0; e < N_EDGES; e += gridDim.x * BLK) {
        int t = etype[e];
        int s = srci[e], d = dsti[e];
        float acc[HID];
#pragma unroll
        for (int j = 0; j < HID; ++j) acc[j] = b1[t * HID + j];
        const float* w = W1 + (size_t)t * 2 * EMB_DIM * HID;
        for (int k = 0; k < EMB_DIM; ++k) {
            float x = emb[(size_t)s * EMB_DIM + k];
#pragma unroll
            for (int j = 0; j < HID; ++j) acc[j] = fmaf(x, w[k * HID + j], acc[j]);
        }
        for (int k = 0; k < EMB_DIM; ++k) {
            float x = emb[(size_t)d * EMB_DIM + k];
#pragma unroll
            for (int j = 0; j < HID; ++j) acc[j] = fmaf(x, w[(EMB_DIM + k) * HID + j], acc[j]);
        }
        float sc = b2[t];
#pragma unroll
        for (int j = 0; j < HID; ++j) {
            float h = acc[j];
            h = (h > 0.f) ? h : 0.01f * h;
            sc = fmaf(h, W2[t * HID + j], sc);
        }
        out[e] = sc;
    }
}

extern "C" void kernel_launch(void* const* d_in, const int* in_sizes, int n_in,
                              void* d_out, int out_size, void* d_ws, size_t ws_size,
                              hipStream_t stream) {
    const float* emb   = (const float*)d_in[0];
    const int*   eidx  = (const int*)d_in[1];
    const int*   etype = (const int*)d_in[2];
    const float* W1    = (const float*)d_in[3];
    const float* b1    = (const float*)d_in[4];
    const float* W2    = (const float*)d_in[5];
    const float* b2    = (const float*)d_in[6];
    float* out = (float*)d_out;
    const int* srci = eidx;
    const int* dsti = eidx + N_EDGES;

    if (ws_size >= NEED16) {
        int*  ws    = (int*)d_ws;
        int2* emb16 = (int2*)((char*)d_ws + EMB16_OFF);
        h2*   w16   = (h2*)((char*)d_ws + W16_OFF);
        prep_k<<<PREP_BLOCKS, BLK, 0, stream>>>(etype, ws, emb, emb16, W1, w16);
        scatter_k<<<CHUNKS, BLK, 0, stream>>>(etype, ws);
        score16_k<<<SCORE_BLOCKS + COPY_BLOCKS, BLK, 0, stream>>>(
            (const unsigned short*)emb16, emb, srci, dsti, ws,
            w16, b1, W2, b2, out);
    } else {
        fallback_k<<<2048, BLK, 0, stream>>>(emb, srci, dsti, etype, W1, b1, W2, b2, out);
    }
}